// Round 16
// baseline (127.569 us; speedup 1.0000x reference)
//
#include <hip/hip_runtime.h>
#include <math.h>

#define Bn 4
#define Tn 12
#define Nn 512
#define Dn 128
#define Ln 4
#define Hn 64
#define NNe (Nn*Nn)

typedef __attribute__((ext_vector_type(8))) short short8;
typedef __attribute__((ext_vector_type(4))) float f32x4;

__device__ __forceinline__ unsigned short f2bf(float f) {
    unsigned int u = __float_as_uint(f);
    unsigned int r = (u + 0x7FFF + ((u >> 16) & 1)) >> 16;   // RNE
    return (unsigned short)r;
}
__device__ __forceinline__ float bf2f(unsigned short s) {
    return __uint_as_float(((unsigned int)s) << 16);
}

// ============ K1a: h[r][lag*64+n] = relu(x_lag @ W1[lag] + b1[lag]) (MFMA) ============
// Unchanged from R14/R15 (proven: no spill, ~0 conflicts). Grid (64,4) = 256 blocks.
// Also zeroes maxslot[0..3] and the mm2 spin counter (slot 4).
__global__ __launch_bounds__(256) void k_enc_a(
    const float* __restrict__ x, const float* __restrict__ W1, const float* __restrict__ b1,
    unsigned short* __restrict__ hb, unsigned int* __restrict__ maxslot)
{
    __shared__ __align__(16) unsigned short xA[32*136];   // A-tile [m=32][k=128]
    __shared__ __align__(16) unsigned short w1T[64*136];  // B-tile [n=64][k=128]
    int tid = threadIdx.x;
    int rg = blockIdx.x, lag = blockIdx.y;
    if (rg == 0 && lag == 0 && tid < 8) maxslot[tid] = 0u;   // 4 max slots + counter + pad
    int r0 = rg * 32;                     // 32 rows, never straddles a batch
    int bb = r0 >> 9, n0 = r0 & 511;

    {   // stage x tile: 32 contiguous rows fp32 -> bf16 (coalesced f4 reads)
        const float4* xs = (const float4*)(x + ((size_t)(bb*Tn + (Tn-1-lag))*Nn + n0)*Dn);
        for (int v = tid; v < 1024; v += 256) {
            float4 f = xs[v];
            int row = v >> 5, c4 = v & 31;
            ushort4 o = { f2bf(f.x), f2bf(f.y), f2bf(f.z), f2bf(f.w) };
            *(ushort4*)&xA[row*136 + c4*4] = o;
        }
    }
    {   // stage W1[lag]^T: thread owns (n, k-octet); 8 coalesced scalar reads + 1 b128 write
        int n = tid & 63, kq = tid >> 6;
        const float* Wp = W1 + (size_t)lag*Dn*Hn;
        #pragma unroll
        for (int r = 0; r < 4; ++r) {
            int k0 = (r*4 + kq)*8;
            unsigned short tmp[8];
            #pragma unroll
            for (int j = 0; j < 8; ++j) tmp[j] = f2bf(Wp[(size_t)(k0+j)*Hn + n]);
            *(short8*)&w1T[n*136 + k0] = *(const short8*)tmp;
        }
    }
    __syncthreads();

    int wv = __builtin_amdgcn_readfirstlane(tid >> 6);
    int lane = tid & 63;
    int wm = wv >> 1, wn = wv & 1;
    int m = lane & 15, q = lane >> 4;
    f32x4 acc[2] = {{0.f,0.f,0.f,0.f},{0.f,0.f,0.f,0.f}};
    #pragma unroll
    for (int ks = 0; ks < 4; ++ks) {
        short8 af = *(const short8*)&xA[(wm*16 + m)*136 + ks*32 + q*8];
        #pragma unroll
        for (int nt = 0; nt < 2; ++nt) {
            short8 bg = *(const short8*)&w1T[(wn*32 + nt*16 + m)*136 + ks*32 + q*8];
            acc[nt] = __builtin_amdgcn_mfma_f32_16x16x32_bf16(af, bg, acc[nt], 0, 0, 0);
        }
    }
    int colL = lane & 15, rq = lane >> 4;
    #pragma unroll
    for (int nt = 0; nt < 2; ++nt) {
        int ncol = wn*32 + nt*16 + colL;
        float bv = b1[lag*Hn + ncol];
        #pragma unroll
        for (int reg = 0; reg < 4; ++reg) {
            int rowL = wm*16 + rq*4 + reg;
            hb[(size_t)(r0+rowL)*256 + lag*64 + ncol] = f2bf(fmaxf(acc[nt][reg] + bv, 0.f));
        }
    }
}

// ============ K1bc: agg = 0.25*(h@W2stacked + sum b2) then sp/tp = agg@Ws1 (fused) ============
__global__ __launch_bounds__(256) void k_enc_bc(
    const unsigned short* __restrict__ hb, const float* __restrict__ W2,
    const float* __restrict__ b2, const float* __restrict__ Ws1,
    const float* __restrict__ bs1,
    unsigned short* __restrict__ spb, unsigned short* __restrict__ tpb)
{
    __shared__ __align__(16) unsigned short hA[16*264];    // A-tile [m=16][k=256]  8448 B
    __shared__ __align__(16) unsigned short wT[64*264];    // B-tile union: w2T 64x264 / wsT 128x136
    __shared__ __align__(16) unsigned short aggA[16*136];  // A-tile [m=16][k=128]  4352 B
    int tid = threadIdx.x;
    int wv = __builtin_amdgcn_readfirstlane(tid >> 6);
    int lane = tid & 63;
    int r0 = blockIdx.x * 16;             // 16 rows, never straddles a batch

    for (int v = tid; v < 512; v += 256) {   // stage hA: 16 rows x 256 bf16, b128
        int row = v >> 5, c = v & 31;
        *(short8*)&hA[row*264 + c*8] = *(const short8*)(hb + (size_t)(r0+row)*256 + c*8);
    }

    int m = lane & 15, q = lane >> 4;
    int colL = lane & 15, rq = lane >> 4;

    // ---- Phase B: aggA = 0.25*(hA @ W2stacked + sum_l b2[l]), two 64-col chunks ----
    for (int ch = 0; ch < 2; ++ch) {
        __syncthreads();
        {   // stage w2T [n=64][k=256]: register transpose, b128 writes
            int n = tid & 63, kq = tid >> 6;
            #pragma unroll
            for (int r = 0; r < 8; ++r) {
                int k0 = (r*4 + kq)*8;
                unsigned short tmp[8];
                #pragma unroll
                for (int j = 0; j < 8; ++j) tmp[j] = f2bf(W2[(size_t)(k0+j)*Dn + ch*64 + n]);
                *(short8*)&wT[n*264 + k0] = *(const short8*)tmp;
            }
        }
        __syncthreads();
        f32x4 acc = {0.f,0.f,0.f,0.f};
        #pragma unroll
        for (int ks = 0; ks < 8; ++ks) {
            short8 af = *(const short8*)&hA[m*264 + ks*32 + q*8];
            short8 bg = *(const short8*)&wT[(wv*16 + m)*264 + ks*32 + q*8];
            acc = __builtin_amdgcn_mfma_f32_16x16x32_bf16(af, bg, acc, 0, 0, 0);
        }
        int col = ch*64 + wv*16 + colL;
        float b2s = b2[col] + b2[Dn+col] + b2[2*Dn+col] + b2[3*Dn+col];
        #pragma unroll
        for (int reg = 0; reg < 4; ++reg)
            aggA[(rq*4+reg)*136 + col] = f2bf(0.25f*(acc[reg] + b2s));
    }

    // ---- Phase C: sp = aggA@Ws1[:D]+bs1 ; tp = aggA@Ws1[D:] ----
    for (int tgt = 0; tgt < 2; ++tgt) {
        __syncthreads();
        {   // stage wsT [n=128][k=128]: register transpose
            int n = tid & 127, kq = tid >> 7;
            #pragma unroll
            for (int r = 0; r < 8; ++r) {
                int k0 = (r*2 + kq)*8;
                unsigned short tmp[8];
                #pragma unroll
                for (int j = 0; j < 8; ++j)
                    tmp[j] = f2bf(Ws1[(size_t)(tgt*Dn + k0 + j)*Dn + n]);
                *(short8*)&wT[n*136 + k0] = *(const short8*)tmp;
            }
        }
        __syncthreads();
        f32x4 acc[2] = {{0.f,0.f,0.f,0.f},{0.f,0.f,0.f,0.f}};
        #pragma unroll
        for (int ks = 0; ks < 4; ++ks) {
            short8 af = *(const short8*)&aggA[m*136 + ks*32 + q*8];
            #pragma unroll
            for (int nt = 0; nt < 2; ++nt) {
                short8 bg = *(const short8*)&wT[(wv*32 + nt*16 + m)*136 + ks*32 + q*8];
                acc[nt] = __builtin_amdgcn_mfma_f32_16x16x32_bf16(af, bg, acc[nt], 0, 0, 0);
            }
        }
        unsigned short* dst = tgt ? tpb : spb;
        #pragma unroll
        for (int nt = 0; nt < 2; ++nt) {
            int n = wv*32 + nt*16 + colL;
            float bv = tgt ? 0.f : bs1[n];         // fold bs1 into sp
            #pragma unroll
            for (int reg = 0; reg < 4; ++reg)
                dst[(size_t)(r0 + rq*4 + reg)*Dn + n] = f2bf(acc[nt][reg] + bv);
        }
    }
}

// ============ K2: pairwise scorer -> adj bf16 row-major + transposed ============
__global__ __launch_bounds__(256) void k_score(
    const unsigned short* __restrict__ spb, const unsigned short* __restrict__ tpb,
    const float* __restrict__ Ws2, const float* __restrict__ bs2,
    unsigned short* __restrict__ adj_b, unsigned short* __restrict__ adj_bt)
{
    __shared__ float spl[64*132];                     // 33 KB
    __shared__ unsigned short tplT[Dn*72];            // 18 KB
    int tid = threadIdx.x;
    int wv = __builtin_amdgcn_readfirstlane(tid >> 6);
    int lane = tid & 63;
    int bz = blockIdx.z;
    int i0b = blockIdx.y * 64, j0b = blockIdx.x * 64;
    const unsigned short* spr = spb + (size_t)bz*Nn*Dn;
    const unsigned short* tpr = tpb + (size_t)bz*Nn*Dn;

    for (int v = tid; v < 1024; v += 256) {           // sp tile: bf16 -> fp32 LDS
        int row = v >> 4, c = v & 15;
        const unsigned short* src = spr + (size_t)(i0b+row)*Dn + c*8;
        ushort4 u0 = *(const ushort4*)src;
        ushort4 u1 = *(const ushort4*)(src + 4);
        float4 f0 = { bf2f(u0.x), bf2f(u0.y), bf2f(u0.z), bf2f(u0.w) };
        float4 f1 = { bf2f(u1.x), bf2f(u1.y), bf2f(u1.z), bf2f(u1.w) };
        *(float4*)&spl[row*132 + c*8]     = f0;
        *(float4*)&spl[row*132 + c*8 + 4] = f1;
    }
    {   // tp tile transposed, bf16
        int j = tid & 63, kq = tid >> 6;
        for (int p = 0; p < 4; ++p) {
            int k8 = p*4 + kq;
            short8 tv = *(const short8*)(tpr + (size_t)(j0b+j)*Dn + k8*8);
            #pragma unroll
            for (int t = 0; t < 8; ++t) tplT[(k8*8+t)*72 + j] = (unsigned short)tv[t];
        }
    }
    __syncthreads();

    int iq = lane >> 4, jq = lane & 15;
    int iw = wv*16 + iq*4;
    float acc[4][4] = {};
    for (int k8 = 0; k8 < 16; ++k8) {
        float4 wa = *(const float4*)(Ws2 + k8*8);     // uniform -> scalar path
        float4 wb = *(const float4*)(Ws2 + k8*8 + 4);
        float4 sA[4], sB[4];
        #pragma unroll
        for (int ii = 0; ii < 4; ++ii) {
            sA[ii] = *(const float4*)&spl[(iw+ii)*132 + k8*8];
            sB[ii] = *(const float4*)&spl[(iw+ii)*132 + k8*8 + 4];
        }
        ushort4 t4[8];
        #pragma unroll
        for (int kk = 0; kk < 8; ++kk) t4[kk] = *(const ushort4*)&tplT[(k8*8+kk)*72 + jq*4];
        #pragma unroll
        for (int kk = 0; kk < 8; ++kk) {
            float w = (kk < 4) ? ((const float*)&wa)[kk] : ((const float*)&wb)[kk-4];
            float tv0 = bf2f(t4[kk].x), tv1 = bf2f(t4[kk].y);
            float tv2 = bf2f(t4[kk].z), tv3 = bf2f(t4[kk].w);
            #pragma unroll
            for (int ii = 0; ii < 4; ++ii) {
                float s = (kk < 4) ? ((const float*)&sA[ii])[kk] : ((const float*)&sB[ii])[kk-4];
                acc[ii][0] += fmaxf(s + tv0, 0.f)*w;
                acc[ii][1] += fmaxf(s + tv1, 0.f)*w;
                acc[ii][2] += fmaxf(s + tv2, 0.f)*w;
                acc[ii][3] += fmaxf(s + tv3, 0.f)*w;
            }
        }
    }
    float bsv = bs2[0];
    int i0 = i0b + iw;
    int j0 = j0b + jq*4;
    float vals[4][4];
    #pragma unroll
    for (int ii = 0; ii < 4; ++ii) {
        int i = i0 + ii;
        #pragma unroll
        for (int jj = 0; jj < 4; ++jj) {
            float z = acc[ii][jj] + bsv;
            float sc = 1.f/(1.f + __expf(-z));
            int j = j0 + jj;
            vals[ii][jj] = (sc > 0.1f && i != j) ? sc : 0.f;
        }
    }
    size_t base = (size_t)bz << 18;
    #pragma unroll
    for (int ii = 0; ii < 4; ++ii) {
        ushort4 rv = make_ushort4(f2bf(vals[ii][0]), f2bf(vals[ii][1]),
                                  f2bf(vals[ii][2]), f2bf(vals[ii][3]));
        *(ushort4*)(adj_b + base + (size_t)(i0+ii)*Nn + j0) = rv;
    }
    #pragma unroll
    for (int jj = 0; jj < 4; ++jj) {
        ushort4 cv = make_ushort4(f2bf(vals[0][jj]), f2bf(vals[1][jj]),
                                  f2bf(vals[2][jj]), f2bf(vals[3][jj]));
        *(ushort4*)(adj_bt + base + (size_t)(j0+jj)*Nn + i0) = cv;
    }
}

// ============ K3: a2 = adj @ adj (MFMA, 64x64 tile, BK=64, reg double-buffer) ============
__global__ __launch_bounds__(256) void k_mm1(
    const unsigned short* __restrict__ adj_b, const unsigned short* __restrict__ adj_bt,
    unsigned short* __restrict__ a2b)
{
    __shared__ unsigned short Als[64*72];
    __shared__ unsigned short Bls[64*72];
    int tid = threadIdx.x;
    int wv = __builtin_amdgcn_readfirstlane(tid >> 6);
    int lane = tid & 63;
    int b = blockIdx.z, i0 = blockIdx.y*64, j0 = blockIdx.x*64;
    size_t base = (size_t)b << 18;
    const unsigned short* Ab = adj_b + base;
    const unsigned short* Bb = adj_bt + base;
    int wm = wv >> 1, wn = wv & 1;
    int m = lane & 15, q = lane >> 4;
    int sr = tid >> 2, sc = (tid & 3)*16;
    f32x4 acc[2][2];
    #pragma unroll
    for (int mt = 0; mt < 2; ++mt)
        #pragma unroll
        for (int nt = 0; nt < 2; ++nt) acc[mt][nt] = (f32x4){0.f,0.f,0.f,0.f};
    short8 pa0, pa1, pb0, pb1;
    pa0 = *(const short8*)(Ab + (size_t)(i0+sr)*Nn + sc);
    pa1 = *(const short8*)(Ab + (size_t)(i0+sr)*Nn + sc + 8);
    pb0 = *(const short8*)(Bb + (size_t)(j0+sr)*Nn + sc);
    pb1 = *(const short8*)(Bb + (size_t)(j0+sr)*Nn + sc + 8);
    for (int kt = 0; kt < 8; ++kt) {
        *(short8*)&Als[sr*72 + sc]     = pa0;
        *(short8*)&Als[sr*72 + sc + 8] = pa1;
        *(short8*)&Bls[sr*72 + sc]     = pb0;
        *(short8*)&Bls[sr*72 + sc + 8] = pb1;
        __syncthreads();
        if (kt < 7) {
            int k0 = (kt+1)*64;
            pa0 = *(const short8*)(Ab + (size_t)(i0+sr)*Nn + k0 + sc);
            pa1 = *(const short8*)(Ab + (size_t)(i0+sr)*Nn + k0 + sc + 8);
            pb0 = *(const short8*)(Bb + (size_t)(j0+sr)*Nn + k0 + sc);
            pb1 = *(const short8*)(Bb + (size_t)(j0+sr)*Nn + k0 + sc + 8);
        }
        #pragma unroll
        for (int ks = 0; ks < 2; ++ks) {
            short8 af[2], bg[2];
            #pragma unroll
            for (int mt = 0; mt < 2; ++mt) af[mt] = *(const short8*)&Als[(wm*32+mt*16+m)*72 + ks*32 + q*8];
            #pragma unroll
            for (int nt = 0; nt < 2; ++nt) bg[nt] = *(const short8*)&Bls[(wn*32+nt*16+m)*72 + ks*32 + q*8];
            #pragma unroll
            for (int mt = 0; mt < 2; ++mt)
                #pragma unroll
                for (int nt = 0; nt < 2; ++nt)
                    acc[mt][nt] = __builtin_amdgcn_mfma_f32_16x16x32_bf16(af[mt], bg[nt], acc[mt][nt], 0, 0, 0);
        }
        __syncthreads();
    }
    int col = lane & 15, rq = lane >> 4;
    #pragma unroll
    for (int mt = 0; mt < 2; ++mt)
        #pragma unroll
        for (int nt = 0; nt < 2; ++nt)
            #pragma unroll
            for (int reg = 0; reg < 4; ++reg) {
                int i = i0 + wm*32 + mt*16 + rq*4 + reg;
                int j = j0 + wn*32 + nt*16 + col;
                a2b[base + (size_t)i*Nn + j] = f2bf(acc[mt][nt][reg]);
            }
}

// ============ K4: out = (adj + 0.5*a2 + 0.25*(a2@adj)) / (max+1e-8), spin-fused norm ============
// 256 blocks = 256 CUs (all resident, 18.5 KB LDS): per-batch atomicMax -> threadfence ->
// done-counter; poll counter (device-scope atomics are XCD-coherent), then scale the
// register-held tile and do the single final store. Removes k_norm dispatch + 8 MB traffic.
__global__ __launch_bounds__(256) void k_mm2(
    const unsigned short* __restrict__ adj_b, const unsigned short* __restrict__ adj_bt,
    const unsigned short* __restrict__ a2b,
    float* __restrict__ out, unsigned int* __restrict__ maxslot)
{
    __shared__ unsigned short Als[64*72];
    __shared__ unsigned short Bls[64*72];
    __shared__ float red[4];
    __shared__ float gmax;
    int tid = threadIdx.x;
    int wv = __builtin_amdgcn_readfirstlane(tid >> 6);
    int lane = tid & 63;
    int b = blockIdx.z, i0 = blockIdx.y*64, j0 = blockIdx.x*64;
    size_t base = (size_t)b << 18;
    const unsigned short* Ab = a2b + base;       // A = a2
    const unsigned short* Bb = adj_bt + base;    // B = adj (transposed layout)
    int wm = wv >> 1, wn = wv & 1;
    int m = lane & 15, q = lane >> 4;
    int sr = tid >> 2, sc = (tid & 3)*16;
    f32x4 acc[2][2];
    #pragma unroll
    for (int mt = 0; mt < 2; ++mt)
        #pragma unroll
        for (int nt = 0; nt < 2; ++nt) acc[mt][nt] = (f32x4){0.f,0.f,0.f,0.f};
    short8 pa0, pa1, pb0, pb1;
    pa0 = *(const short8*)(Ab + (size_t)(i0+sr)*Nn + sc);
    pa1 = *(const short8*)(Ab + (size_t)(i0+sr)*Nn + sc + 8);
    pb0 = *(const short8*)(Bb + (size_t)(j0+sr)*Nn + sc);
    pb1 = *(const short8*)(Bb + (size_t)(j0+sr)*Nn + sc + 8);
    for (int kt = 0; kt < 8; ++kt) {
        *(short8*)&Als[sr*72 + sc]     = pa0;
        *(short8*)&Als[sr*72 + sc + 8] = pa1;
        *(short8*)&Bls[sr*72 + sc]     = pb0;
        *(short8*)&Bls[sr*72 + sc + 8] = pb1;
        __syncthreads();
        if (kt < 7) {
            int k0 = (kt+1)*64;
            pa0 = *(const short8*)(Ab + (size_t)(i0+sr)*Nn + k0 + sc);
            pa1 = *(const short8*)(Ab + (size_t)(i0+sr)*Nn + k0 + sc + 8);
            pb0 = *(const short8*)(Bb + (size_t)(j0+sr)*Nn + k0 + sc);
            pb1 = *(const short8*)(Bb + (size_t)(j0+sr)*Nn + k0 + sc + 8);
        }
        #pragma unroll
        for (int ks = 0; ks < 2; ++ks) {
            short8 af[2], bg[2];
            #pragma unroll
            for (int mt = 0; mt < 2; ++mt) af[mt] = *(const short8*)&Als[(wm*32+mt*16+m)*72 + ks*32 + q*8];
            #pragma unroll
            for (int nt = 0; nt < 2; ++nt) bg[nt] = *(const short8*)&Bls[(wn*32+nt*16+m)*72 + ks*32 + q*8];
            #pragma unroll
            for (int mt = 0; mt < 2; ++mt)
                #pragma unroll
                for (int nt = 0; nt < 2; ++nt)
                    acc[mt][nt] = __builtin_amdgcn_mfma_f32_16x16x32_bf16(af[mt], bg[nt], acc[mt][nt], 0, 0, 0);
        }
        __syncthreads();
    }
    int col = lane & 15, rq = lane >> 4;
    float lmax = 0.f;
    float e[2][2][4];
    const unsigned short* adjp = adj_b + base;
    #pragma unroll
    for (int mt = 0; mt < 2; ++mt)
        #pragma unroll
        for (int nt = 0; nt < 2; ++nt)
            #pragma unroll
            for (int reg = 0; reg < 4; ++reg) {
                int i = i0 + wm*32 + mt*16 + rq*4 + reg;
                int j = j0 + wn*32 + nt*16 + col;
                size_t off = (size_t)i*Nn + j;
                float v = bf2f(adjp[off]) + 0.5f*bf2f(Ab[off]) + 0.25f*acc[mt][nt][reg];
                e[mt][nt][reg] = v;
                lmax = fmaxf(lmax, v);
            }
    #pragma unroll
    for (int s = 1; s < 64; s <<= 1) lmax = fmaxf(lmax, __shfl_xor(lmax, s, 64));
    if (lane == 0) red[wv] = lmax;
    __syncthreads();
    unsigned int* cnt = maxslot + 4;
    if (tid == 0) {
        float mx = fmaxf(fmaxf(red[0], red[1]), fmaxf(red[2], red[3]));
        atomicMax(maxslot + b, __float_as_uint(mx));
        __threadfence();                         // max visible before counter bump
        atomicAdd(cnt, 1u);
        while (atomicAdd(cnt, 0u) < 256u) __builtin_amdgcn_s_sleep(16);
        gmax = __uint_as_float(atomicMax(maxslot + b, 0u));   // device-scope read
    }
    __syncthreads();
    float inv = 1.f/(gmax + 1e-8f);
    #pragma unroll
    for (int mt = 0; mt < 2; ++mt)
        #pragma unroll
        for (int nt = 0; nt < 2; ++nt)
            #pragma unroll
            for (int reg = 0; reg < 4; ++reg) {
                int i = i0 + wm*32 + mt*16 + rq*4 + reg;
                int j = j0 + wn*32 + nt*16 + col;
                out[base + (size_t)i*Nn + j] = e[mt][nt][reg]*inv;
            }
}

extern "C" void kernel_launch(void* const* d_in, const int* in_sizes, int n_in,
                              void* d_out, int out_size, void* d_ws, size_t ws_size,
                              hipStream_t stream) {
    const float* x   = (const float*)d_in[0];
    const float* W1  = (const float*)d_in[1];
    const float* b1  = (const float*)d_in[2];
    const float* W2  = (const float*)d_in[3];
    const float* b2  = (const float*)d_in[4];
    const float* Ws1 = (const float*)d_in[5];
    const float* bs1 = (const float*)d_in[6];
    const float* Ws2 = (const float*)d_in[7];
    const float* bs2 = (const float*)d_in[8];
    float* out = (float*)d_out;

    unsigned char* wsb = (unsigned char*)d_ws;
    unsigned short* spb    = (unsigned short*)(wsb);                    // 512 KB
    unsigned short* tpb    = (unsigned short*)(wsb + (512u<<10));       // 512 KB
    unsigned short* adj_b  = (unsigned short*)(wsb + (1024u<<10));      // 2 MB
    unsigned short* adj_bt = (unsigned short*)(wsb + (3072u<<10));      // 2 MB
    unsigned short* a2b    = (unsigned short*)(wsb + (5120u<<10));      // 2 MB
    unsigned int*   maxslot= (unsigned int*)(wsb + (7168u<<10));        // 4 max + counter
    unsigned short* hb     = (unsigned short*)(wsb + (7172u<<10));      // 1 MB  [row][256]

    k_enc_a <<<dim3(64, 4),   256, 0, stream>>>(x, W1, b1, hb, maxslot);
    k_enc_bc<<<dim3(128),     256, 0, stream>>>(hb, W2, b2, Ws1, bs1, spb, tpb);
    k_score <<<dim3(8, 8, Bn),256, 0, stream>>>(spb, tpb, Ws2, bs2, adj_b, adj_bt);
    k_mm1   <<<dim3(8, 8, Bn),256, 0, stream>>>(adj_b, adj_bt, a2b);
    k_mm2   <<<dim3(8, 8, Bn),256, 0, stream>>>(adj_b, adj_bt, a2b, out, maxslot);
}

// Round 17
// 123.576 us; speedup vs baseline: 1.0323x; 1.0323x over previous
//
#include <hip/hip_runtime.h>
#include <math.h>

#define Bn 4
#define Tn 12
#define Nn 512
#define Dn 128
#define Ln 4
#define Hn 64
#define NNe (Nn*Nn)

typedef __attribute__((ext_vector_type(8))) short short8;
typedef __attribute__((ext_vector_type(4))) float f32x4;

__device__ __forceinline__ unsigned short f2bf(float f) {
    unsigned int u = __float_as_uint(f);
    unsigned int r = (u + 0x7FFF + ((u >> 16) & 1)) >> 16;   // RNE
    return (unsigned short)r;
}
__device__ __forceinline__ float bf2f(unsigned short s) {
    return __uint_as_float(((unsigned int)s) << 16);
}

// ============ K1a: h[r][lag*64+n] = relu(x_lag @ W1[lag] + b1[lag]) (MFMA) ============
// R14/R15 proven config: no spill, ~0 conflicts. Grid (64,4) = 256 blocks.
__global__ __launch_bounds__(256) void k_enc_a(
    const float* __restrict__ x, const float* __restrict__ W1, const float* __restrict__ b1,
    unsigned short* __restrict__ hb, unsigned int* __restrict__ maxslot)
{
    __shared__ __align__(16) unsigned short xA[32*136];   // A-tile [m=32][k=128]
    __shared__ __align__(16) unsigned short w1T[64*136];  // B-tile [n=64][k=128]
    int tid = threadIdx.x;
    int rg = blockIdx.x, lag = blockIdx.y;
    if (rg == 0 && lag == 0 && tid < Bn) maxslot[tid] = 0u;
    int r0 = rg * 32;                     // 32 rows, never straddles a batch
    int bb = r0 >> 9, n0 = r0 & 511;

    {   // stage x tile: 32 contiguous rows fp32 -> bf16 (coalesced f4 reads)
        const float4* xs = (const float4*)(x + ((size_t)(bb*Tn + (Tn-1-lag))*Nn + n0)*Dn);
        for (int v = tid; v < 1024; v += 256) {
            float4 f = xs[v];
            int row = v >> 5, c4 = v & 31;
            ushort4 o = { f2bf(f.x), f2bf(f.y), f2bf(f.z), f2bf(f.w) };
            *(ushort4*)&xA[row*136 + c4*4] = o;
        }
    }
    {   // stage W1[lag]^T: thread owns (n, k-octet); 8 coalesced scalar reads + 1 b128 write
        int n = tid & 63, kq = tid >> 6;
        const float* Wp = W1 + (size_t)lag*Dn*Hn;
        #pragma unroll
        for (int r = 0; r < 4; ++r) {
            int k0 = (r*4 + kq)*8;
            unsigned short tmp[8];
            #pragma unroll
            for (int j = 0; j < 8; ++j) tmp[j] = f2bf(Wp[(size_t)(k0+j)*Hn + n]);
            *(short8*)&w1T[n*136 + k0] = *(const short8*)tmp;
        }
    }
    __syncthreads();

    int wv = __builtin_amdgcn_readfirstlane(tid >> 6);
    int lane = tid & 63;
    int wm = wv >> 1, wn = wv & 1;
    int m = lane & 15, q = lane >> 4;
    f32x4 acc[2] = {{0.f,0.f,0.f,0.f},{0.f,0.f,0.f,0.f}};
    #pragma unroll
    for (int ks = 0; ks < 4; ++ks) {
        short8 af = *(const short8*)&xA[(wm*16 + m)*136 + ks*32 + q*8];
        #pragma unroll
        for (int nt = 0; nt < 2; ++nt) {
            short8 bg = *(const short8*)&w1T[(wn*32 + nt*16 + m)*136 + ks*32 + q*8];
            acc[nt] = __builtin_amdgcn_mfma_f32_16x16x32_bf16(af, bg, acc[nt], 0, 0, 0);
        }
    }
    int colL = lane & 15, rq = lane >> 4;
    #pragma unroll
    for (int nt = 0; nt < 2; ++nt) {
        int ncol = wn*32 + nt*16 + colL;
        float bv = b1[lag*Hn + ncol];
        #pragma unroll
        for (int reg = 0; reg < 4; ++reg) {
            int rowL = wm*16 + rq*4 + reg;
            hb[(size_t)(r0+rowL)*256 + lag*64 + ncol] = f2bf(fmaxf(acc[nt][reg] + bv, 0.f));
        }
    }
}

// ============ K1bc: agg = 0.25*(h@W2stacked + sum b2) then sp/tp = agg@Ws1 (fused) ============
__global__ __launch_bounds__(256) void k_enc_bc(
    const unsigned short* __restrict__ hb, const float* __restrict__ W2,
    const float* __restrict__ b2, const float* __restrict__ Ws1,
    const float* __restrict__ bs1,
    unsigned short* __restrict__ spb, unsigned short* __restrict__ tpb)
{
    __shared__ __align__(16) unsigned short hA[16*264];    // A-tile [m=16][k=256]
    __shared__ __align__(16) unsigned short wT[64*264];    // B-tile union: w2T / wsT
    __shared__ __align__(16) unsigned short aggA[16*136];  // A-tile [m=16][k=128]
    int tid = threadIdx.x;
    int wv = __builtin_amdgcn_readfirstlane(tid >> 6);
    int lane = tid & 63;
    int r0 = blockIdx.x * 16;             // 16 rows, never straddles a batch

    for (int v = tid; v < 512; v += 256) {   // stage hA: 16 rows x 256 bf16, b128
        int row = v >> 5, c = v & 31;
        *(short8*)&hA[row*264 + c*8] = *(const short8*)(hb + (size_t)(r0+row)*256 + c*8);
    }

    int m = lane & 15, q = lane >> 4;
    int colL = lane & 15, rq = lane >> 4;

    // ---- Phase B: aggA = 0.25*(hA @ W2stacked + sum_l b2[l]), two 64-col chunks ----
    for (int ch = 0; ch < 2; ++ch) {
        __syncthreads();
        {   // stage w2T [n=64][k=256]: register transpose, b128 writes
            int n = tid & 63, kq = tid >> 6;
            #pragma unroll
            for (int r = 0; r < 8; ++r) {
                int k0 = (r*4 + kq)*8;
                unsigned short tmp[8];
                #pragma unroll
                for (int j = 0; j < 8; ++j) tmp[j] = f2bf(W2[(size_t)(k0+j)*Dn + ch*64 + n]);
                *(short8*)&wT[n*264 + k0] = *(const short8*)tmp;
            }
        }
        __syncthreads();
        f32x4 acc = {0.f,0.f,0.f,0.f};
        #pragma unroll
        for (int ks = 0; ks < 8; ++ks) {
            short8 af = *(const short8*)&hA[m*264 + ks*32 + q*8];
            short8 bg = *(const short8*)&wT[(wv*16 + m)*264 + ks*32 + q*8];
            acc = __builtin_amdgcn_mfma_f32_16x16x32_bf16(af, bg, acc, 0, 0, 0);
        }
        int col = ch*64 + wv*16 + colL;
        float b2s = b2[col] + b2[Dn+col] + b2[2*Dn+col] + b2[3*Dn+col];
        #pragma unroll
        for (int reg = 0; reg < 4; ++reg)
            aggA[(rq*4+reg)*136 + col] = f2bf(0.25f*(acc[reg] + b2s));
    }

    // ---- Phase C: sp = aggA@Ws1[:D]+bs1 ; tp = aggA@Ws1[D:] ----
    for (int tgt = 0; tgt < 2; ++tgt) {
        __syncthreads();
        {   // stage wsT [n=128][k=128]: register transpose
            int n = tid & 127, kq = tid >> 7;
            #pragma unroll
            for (int r = 0; r < 8; ++r) {
                int k0 = (r*2 + kq)*8;
                unsigned short tmp[8];
                #pragma unroll
                for (int j = 0; j < 8; ++j)
                    tmp[j] = f2bf(Ws1[(size_t)(tgt*Dn + k0 + j)*Dn + n]);
                *(short8*)&wT[n*136 + k0] = *(const short8*)tmp;
            }
        }
        __syncthreads();
        f32x4 acc[2] = {{0.f,0.f,0.f,0.f},{0.f,0.f,0.f,0.f}};
        #pragma unroll
        for (int ks = 0; ks < 4; ++ks) {
            short8 af = *(const short8*)&aggA[m*136 + ks*32 + q*8];
            #pragma unroll
            for (int nt = 0; nt < 2; ++nt) {
                short8 bg = *(const short8*)&wT[(wv*32 + nt*16 + m)*136 + ks*32 + q*8];
                acc[nt] = __builtin_amdgcn_mfma_f32_16x16x32_bf16(af, bg, acc[nt], 0, 0, 0);
            }
        }
        unsigned short* dst = tgt ? tpb : spb;
        #pragma unroll
        for (int nt = 0; nt < 2; ++nt) {
            int n = wv*32 + nt*16 + colL;
            float bv = tgt ? 0.f : bs1[n];         // fold bs1 into sp
            #pragma unroll
            for (int reg = 0; reg < 4; ++reg)
                dst[(size_t)(r0 + rq*4 + reg)*Dn + n] = f2bf(acc[nt][reg] + bv);
        }
    }
}

// ============ K2: pairwise scorer -> adj bf16 row-major + transposed ============
__global__ __launch_bounds__(256) void k_score(
    const unsigned short* __restrict__ spb, const unsigned short* __restrict__ tpb,
    const float* __restrict__ Ws2, const float* __restrict__ bs2,
    unsigned short* __restrict__ adj_b, unsigned short* __restrict__ adj_bt)
{
    __shared__ float spl[64*132];                     // 33 KB
    __shared__ unsigned short tplT[Dn*72];            // 18 KB
    int tid = threadIdx.x;
    int wv = __builtin_amdgcn_readfirstlane(tid >> 6);
    int lane = tid & 63;
    int bz = blockIdx.z;
    int i0b = blockIdx.y * 64, j0b = blockIdx.x * 64;
    const unsigned short* spr = spb + (size_t)bz*Nn*Dn;
    const unsigned short* tpr = tpb + (size_t)bz*Nn*Dn;

    for (int v = tid; v < 1024; v += 256) {           // sp tile: bf16 -> fp32 LDS
        int row = v >> 4, c = v & 15;
        const unsigned short* src = spr + (size_t)(i0b+row)*Dn + c*8;
        ushort4 u0 = *(const ushort4*)src;
        ushort4 u1 = *(const ushort4*)(src + 4);
        float4 f0 = { bf2f(u0.x), bf2f(u0.y), bf2f(u0.z), bf2f(u0.w) };
        float4 f1 = { bf2f(u1.x), bf2f(u1.y), bf2f(u1.z), bf2f(u1.w) };
        *(float4*)&spl[row*132 + c*8]     = f0;
        *(float4*)&spl[row*132 + c*8 + 4] = f1;
    }
    {   // tp tile transposed, bf16
        int j = tid & 63, kq = tid >> 6;
        for (int p = 0; p < 4; ++p) {
            int k8 = p*4 + kq;
            short8 tv = *(const short8*)(tpr + (size_t)(j0b+j)*Dn + k8*8);
            #pragma unroll
            for (int t = 0; t < 8; ++t) tplT[(k8*8+t)*72 + j] = (unsigned short)tv[t];
        }
    }
    __syncthreads();

    int iq = lane >> 4, jq = lane & 15;
    int iw = wv*16 + iq*4;
    float acc[4][4] = {};
    for (int k8 = 0; k8 < 16; ++k8) {
        float4 wa = *(const float4*)(Ws2 + k8*8);     // uniform -> scalar path
        float4 wb = *(const float4*)(Ws2 + k8*8 + 4);
        float4 sA[4], sB[4];
        #pragma unroll
        for (int ii = 0; ii < 4; ++ii) {
            sA[ii] = *(const float4*)&spl[(iw+ii)*132 + k8*8];
            sB[ii] = *(const float4*)&spl[(iw+ii)*132 + k8*8 + 4];
        }
        ushort4 t4[8];
        #pragma unroll
        for (int kk = 0; kk < 8; ++kk) t4[kk] = *(const ushort4*)&tplT[(k8*8+kk)*72 + jq*4];
        #pragma unroll
        for (int kk = 0; kk < 8; ++kk) {
            float w = (kk < 4) ? ((const float*)&wa)[kk] : ((const float*)&wb)[kk-4];
            float tv0 = bf2f(t4[kk].x), tv1 = bf2f(t4[kk].y);
            float tv2 = bf2f(t4[kk].z), tv3 = bf2f(t4[kk].w);
            #pragma unroll
            for (int ii = 0; ii < 4; ++ii) {
                float s = (kk < 4) ? ((const float*)&sA[ii])[kk] : ((const float*)&sB[ii])[kk-4];
                acc[ii][0] += fmaxf(s + tv0, 0.f)*w;
                acc[ii][1] += fmaxf(s + tv1, 0.f)*w;
                acc[ii][2] += fmaxf(s + tv2, 0.f)*w;
                acc[ii][3] += fmaxf(s + tv3, 0.f)*w;
            }
        }
    }
    float bsv = bs2[0];
    int i0 = i0b + iw;
    int j0 = j0b + jq*4;
    float vals[4][4];
    #pragma unroll
    for (int ii = 0; ii < 4; ++ii) {
        int i = i0 + ii;
        #pragma unroll
        for (int jj = 0; jj < 4; ++jj) {
            float z = acc[ii][jj] + bsv;
            float sc = 1.f/(1.f + __expf(-z));
            int j = j0 + jj;
            vals[ii][jj] = (sc > 0.1f && i != j) ? sc : 0.f;
        }
    }
    size_t base = (size_t)bz << 18;
    #pragma unroll
    for (int ii = 0; ii < 4; ++ii) {
        ushort4 rv = make_ushort4(f2bf(vals[ii][0]), f2bf(vals[ii][1]),
                                  f2bf(vals[ii][2]), f2bf(vals[ii][3]));
        *(ushort4*)(adj_b + base + (size_t)(i0+ii)*Nn + j0) = rv;
    }
    #pragma unroll
    for (int jj = 0; jj < 4; ++jj) {
        ushort4 cv = make_ushort4(f2bf(vals[0][jj]), f2bf(vals[1][jj]),
                                  f2bf(vals[2][jj]), f2bf(vals[3][jj]));
        *(ushort4*)(adj_bt + base + (size_t)(j0+jj)*Nn + i0) = cv;
    }
}

// ============ K3: a2 = adj @ adj (MFMA, 64x64 tile, BK=64, reg double-buffer) ============
__global__ __launch_bounds__(256) void k_mm1(
    const unsigned short* __restrict__ adj_b, const unsigned short* __restrict__ adj_bt,
    unsigned short* __restrict__ a2b)
{
    __shared__ unsigned short Als[64*72];
    __shared__ unsigned short Bls[64*72];
    int tid = threadIdx.x;
    int wv = __builtin_amdgcn_readfirstlane(tid >> 6);
    int lane = tid & 63;
    int b = blockIdx.z, i0 = blockIdx.y*64, j0 = blockIdx.x*64;
    size_t base = (size_t)b << 18;
    const unsigned short* Ab = adj_b + base;
    const unsigned short* Bb = adj_bt + base;
    int wm = wv >> 1, wn = wv & 1;
    int m = lane & 15, q = lane >> 4;
    int sr = tid >> 2, sc = (tid & 3)*16;
    f32x4 acc[2][2];
    #pragma unroll
    for (int mt = 0; mt < 2; ++mt)
        #pragma unroll
        for (int nt = 0; nt < 2; ++nt) acc[mt][nt] = (f32x4){0.f,0.f,0.f,0.f};
    short8 pa0, pa1, pb0, pb1;
    pa0 = *(const short8*)(Ab + (size_t)(i0+sr)*Nn + sc);
    pa1 = *(const short8*)(Ab + (size_t)(i0+sr)*Nn + sc + 8);
    pb0 = *(const short8*)(Bb + (size_t)(j0+sr)*Nn + sc);
    pb1 = *(const short8*)(Bb + (size_t)(j0+sr)*Nn + sc + 8);
    for (int kt = 0; kt < 8; ++kt) {
        *(short8*)&Als[sr*72 + sc]     = pa0;
        *(short8*)&Als[sr*72 + sc + 8] = pa1;
        *(short8*)&Bls[sr*72 + sc]     = pb0;
        *(short8*)&Bls[sr*72 + sc + 8] = pb1;
        __syncthreads();
        if (kt < 7) {
            int k0 = (kt+1)*64;
            pa0 = *(const short8*)(Ab + (size_t)(i0+sr)*Nn + k0 + sc);
            pa1 = *(const short8*)(Ab + (size_t)(i0+sr)*Nn + k0 + sc + 8);
            pb0 = *(const short8*)(Bb + (size_t)(j0+sr)*Nn + k0 + sc);
            pb1 = *(const short8*)(Bb + (size_t)(j0+sr)*Nn + k0 + sc + 8);
        }
        #pragma unroll
        for (int ks = 0; ks < 2; ++ks) {
            short8 af[2], bg[2];
            #pragma unroll
            for (int mt = 0; mt < 2; ++mt) af[mt] = *(const short8*)&Als[(wm*32+mt*16+m)*72 + ks*32 + q*8];
            #pragma unroll
            for (int nt = 0; nt < 2; ++nt) bg[nt] = *(const short8*)&Bls[(wn*32+nt*16+m)*72 + ks*32 + q*8];
            #pragma unroll
            for (int mt = 0; mt < 2; ++mt)
                #pragma unroll
                for (int nt = 0; nt < 2; ++nt)
                    acc[mt][nt] = __builtin_amdgcn_mfma_f32_16x16x32_bf16(af[mt], bg[nt], acc[mt][nt], 0, 0, 0);
        }
        __syncthreads();
    }
    int col = lane & 15, rq = lane >> 4;
    #pragma unroll
    for (int mt = 0; mt < 2; ++mt)
        #pragma unroll
        for (int nt = 0; nt < 2; ++nt)
            #pragma unroll
            for (int reg = 0; reg < 4; ++reg) {
                int i = i0 + wm*32 + mt*16 + rq*4 + reg;
                int j = j0 + wn*32 + nt*16 + col;
                a2b[base + (size_t)i*Nn + j] = f2bf(acc[mt][nt][reg]);
            }
}

// ============ K4: out = adj + 0.5*a2 + 0.25*(a2@adj), + per-batch max ============
__global__ __launch_bounds__(256) void k_mm2(
    const unsigned short* __restrict__ adj_b, const unsigned short* __restrict__ adj_bt,
    const unsigned short* __restrict__ a2b,
    float* __restrict__ out, unsigned int* __restrict__ maxslot)
{
    __shared__ unsigned short Als[64*72];
    __shared__ unsigned short Bls[64*72];
    __shared__ float red[4];
    int tid = threadIdx.x;
    int wv = __builtin_amdgcn_readfirstlane(tid >> 6);
    int lane = tid & 63;
    int b = blockIdx.z, i0 = blockIdx.y*64, j0 = blockIdx.x*64;
    size_t base = (size_t)b << 18;
    const unsigned short* Ab = a2b + base;       // A = a2
    const unsigned short* Bb = adj_bt + base;    // B = adj (transposed layout)
    int wm = wv >> 1, wn = wv & 1;
    int m = lane & 15, q = lane >> 4;
    int sr = tid >> 2, sc = (tid & 3)*16;
    f32x4 acc[2][2];
    #pragma unroll
    for (int mt = 0; mt < 2; ++mt)
        #pragma unroll
        for (int nt = 0; nt < 2; ++nt) acc[mt][nt] = (f32x4){0.f,0.f,0.f,0.f};
    short8 pa0, pa1, pb0, pb1;
    pa0 = *(const short8*)(Ab + (size_t)(i0+sr)*Nn + sc);
    pa1 = *(const short8*)(Ab + (size_t)(i0+sr)*Nn + sc + 8);
    pb0 = *(const short8*)(Bb + (size_t)(j0+sr)*Nn + sc);
    pb1 = *(const short8*)(Bb + (size_t)(j0+sr)*Nn + sc + 8);
    for (int kt = 0; kt < 8; ++kt) {
        *(short8*)&Als[sr*72 + sc]     = pa0;
        *(short8*)&Als[sr*72 + sc + 8] = pa1;
        *(short8*)&Bls[sr*72 + sc]     = pb0;
        *(short8*)&Bls[sr*72 + sc + 8] = pb1;
        __syncthreads();
        if (kt < 7) {
            int k0 = (kt+1)*64;
            pa0 = *(const short8*)(Ab + (size_t)(i0+sr)*Nn + k0 + sc);
            pa1 = *(const short8*)(Ab + (size_t)(i0+sr)*Nn + k0 + sc + 8);
            pb0 = *(const short8*)(Bb + (size_t)(j0+sr)*Nn + k0 + sc);
            pb1 = *(const short8*)(Bb + (size_t)(j0+sr)*Nn + k0 + sc + 8);
        }
        #pragma unroll
        for (int ks = 0; ks < 2; ++ks) {
            short8 af[2], bg[2];
            #pragma unroll
            for (int mt = 0; mt < 2; ++mt) af[mt] = *(const short8*)&Als[(wm*32+mt*16+m)*72 + ks*32 + q*8];
            #pragma unroll
            for (int nt = 0; nt < 2; ++nt) bg[nt] = *(const short8*)&Bls[(wn*32+nt*16+m)*72 + ks*32 + q*8];
            #pragma unroll
            for (int mt = 0; mt < 2; ++mt)
                #pragma unroll
                for (int nt = 0; nt < 2; ++nt)
                    acc[mt][nt] = __builtin_amdgcn_mfma_f32_16x16x32_bf16(af[mt], bg[nt], acc[mt][nt], 0, 0, 0);
        }
        __syncthreads();
    }
    int col = lane & 15, rq = lane >> 4;
    float lmax = 0.f;
    const unsigned short* adjp = adj_b + base;
    #pragma unroll
    for (int mt = 0; mt < 2; ++mt)
        #pragma unroll
        for (int nt = 0; nt < 2; ++nt)
            #pragma unroll
            for (int reg = 0; reg < 4; ++reg) {
                int i = i0 + wm*32 + mt*16 + rq*4 + reg;
                int j = j0 + wn*32 + nt*16 + col;
                size_t off = (size_t)i*Nn + j;
                float e = bf2f(adjp[off]) + 0.5f*bf2f(Ab[off]) + 0.25f*acc[mt][nt][reg];
                out[base + off] = e;
                lmax = fmaxf(lmax, e);
            }
    #pragma unroll
    for (int s = 1; s < 64; s <<= 1) lmax = fmaxf(lmax, __shfl_xor(lmax, s, 64));
    if (lane == 0) red[wv] = lmax;
    __syncthreads();
    if (tid == 0) {
        float mx = fmaxf(fmaxf(red[0], red[1]), fmaxf(red[2], red[3]));
        atomicMax(maxslot + b, __float_as_uint(mx));
    }
}

// ============ K5: out /= (max + 1e-8) ============
__global__ __launch_bounds__(256) void k_norm(float* __restrict__ out,
                                              const unsigned int* __restrict__ maxslot)
{
    int idx = blockIdx.x*256 + threadIdx.x;   // float4 index; 65536 per batch
    int b = idx >> 16;
    float m = __uint_as_float(maxslot[b]);
    float inv = 1.f/(m + 1e-8f);
    float4* p = (float4*)out + idx;
    float4 v = *p;
    v.x *= inv; v.y *= inv; v.z *= inv; v.w *= inv;
    *p = v;
}

extern "C" void kernel_launch(void* const* d_in, const int* in_sizes, int n_in,
                              void* d_out, int out_size, void* d_ws, size_t ws_size,
                              hipStream_t stream) {
    const float* x   = (const float*)d_in[0];
    const float* W1  = (const float*)d_in[1];
    const float* b1  = (const float*)d_in[2];
    const float* W2  = (const float*)d_in[3];
    const float* b2  = (const float*)d_in[4];
    const float* Ws1 = (const float*)d_in[5];
    const float* bs1 = (const float*)d_in[6];
    const float* Ws2 = (const float*)d_in[7];
    const float* bs2 = (const float*)d_in[8];
    float* out = (float*)d_out;

    unsigned char* wsb = (unsigned char*)d_ws;
    unsigned short* spb    = (unsigned short*)(wsb);                    // 512 KB
    unsigned short* tpb    = (unsigned short*)(wsb + (512u<<10));       // 512 KB
    unsigned short* adj_b  = (unsigned short*)(wsb + (1024u<<10));      // 2 MB
    unsigned short* adj_bt = (unsigned short*)(wsb + (3072u<<10));      // 2 MB
    unsigned short* a2b    = (unsigned short*)(wsb + (5120u<<10));      // 2 MB
    unsigned int*   maxslot= (unsigned int*)(wsb + (7168u<<10));        // 16 B
    unsigned short* hb     = (unsigned short*)(wsb + (7172u<<10));      // 1 MB  [row][256]

    k_enc_a <<<dim3(64, 4),   256, 0, stream>>>(x, W1, b1, hb, maxslot);
    k_enc_bc<<<dim3(128),     256, 0, stream>>>(hb, W2, b2, Ws1, bs1, spb, tpb);
    k_score <<<dim3(8, 8, Bn),256, 0, stream>>>(spb, tpb, Ws2, bs2, adj_b, adj_bt);
    k_mm1   <<<dim3(8, 8, Bn),256, 0, stream>>>(adj_b, adj_bt, a2b);
    k_mm2   <<<dim3(8, 8, Bn),256, 0, stream>>>(adj_b, adj_bt, a2b, out, maxslot);
    k_norm  <<<dim3(1024),    256, 0, stream>>>(out, maxslot);
}